// Round 8
// baseline (581.626 us; speedup 1.0000x reference)
//
#include <hip/hip_runtime.h>
#include <hip/hip_cooperative_groups.h>

namespace cg = cooperative_groups;

#define IN_F   360
#define HIDN   64
#define NCLS   5
#define BATCH  64
#define SEQ    128
#define NROWS  (BATCH*SEQ)   // 8192

// workspace layout (float offsets)
#define WS_FLAG  0            // int flag: 0 => scale==1 && trans==0 everywhere (fast path ok)
#define WS_WPACK 16           // float4[360*64] = 92160 floats (general path)
#define WS_WFAST 92176        // float2[360*64] = 46080 floats (fast path packed {C*ww, bw})
#define WS_WT4   138256       // 24576 floats (w_ih transposed, float4-packed)
#define WS_XEMB  162832       // (unused; x_emb lives in LDS)
#define WS_GI    687120       // 8192*384 = 3145728
#define WS_HC    3832848      // 64*128 = 8192

#define LOG2E        1.4426950408889634f
#define NEG_HALF_L2E (-0.7213475204444817f)

__device__ __forceinline__ float fast_rcp(float x) { return __builtin_amdgcn_rcpf(x); }
__device__ __forceinline__ float fast_rsq(float x) { return __builtin_amdgcn_rsqf(x); }
__device__ __forceinline__ float sigmoid_(float x) {
    x = fminf(fmaxf(x, -60.0f), 60.0f);
    return fast_rcp(1.0f + exp2f(-LOG2E * x));
}
__device__ __forceinline__ float tanh_(float x) {
    x = fminf(fmaxf(x, -30.0f), 30.0f);
    float e = exp2f(-2.8853900817779268f * x);   // e^{-2x}
    return (1.0f - e) * fast_rcp(1.0f + e);
}
// CRITICAL: __builtin_amdgcn_readlane is (int,int) — bit-cast in and out.
__device__ __forceinline__ float readlane_f(float v, int l) {
    return __int_as_float(__builtin_amdgcn_readlane(__float_as_int(v), l));
}

// ============ ONE cooperative mega-kernel: prep -> wavkan -> gi -> gru -> head
// 256 blocks x 512 threads, grid.sync() between cross-block phases.
// R7 lesson: phase-2 gi is k4-OUTER with acc[32] (no persistent weight array,
// ~45 live regs) so the allocator can't crush it; gru keeps R4's proven
// 3-wave body (w[64] resident at VGPR 68 under launch_bounds min-waves=1).
__global__ __launch_bounds__(512, 1) void mega_kernel(
    const float* __restrict__ x_seq,
    const float* __restrict__ scale, const float* __restrict__ trans,
    const float* __restrict__ ww,    const float* __restrict__ bw,
    const float* __restrict__ bn_g,  const float* __restrict__ bn_b,
    const float* __restrict__ bn_m,  const float* __restrict__ bn_v,
    const float* __restrict__ ln_g,  const float* __restrict__ ln_b,
    const float* __restrict__ wihf,  const float* __restrict__ wihb,
    const float* __restrict__ bihf,  const float* __restrict__ bihb,
    const float* __restrict__ whhf,  const float* __restrict__ bhhf,
    const float* __restrict__ whhb,  const float* __restrict__ bhhb,
    const float* __restrict__ fc1w,  const float* __restrict__ fc1b,
    const float* __restrict__ fc2w,  const float* __restrict__ fc2b,
    float* __restrict__ ws, float* __restrict__ out) {

    __shared__ __align__(16) union SM {
        struct { float2 xs[16 * IN_F]; float xs2[32 * 64]; } s12;  // 46080+8192 B
        struct { float gi_l[64 * 192]; float ex[2][192]; } s3;     // 49152+1536 B
        struct { float hr[128]; float h1[64]; } s4;
    } sm;

    cg::grid_group grid = cg::this_grid();
    int t = threadIdx.x, bid = blockIdx.x;
    float* gi = ws + WS_GI;
    float* hc = ws + WS_HC;

    // ---------------- P0: weight prep + fast-path flag ----------------
    {
        int idx = bid * 512 + t;
        float4* wpack  = (float4*)(ws + WS_WPACK);
        float2* wfast2 = (float2*)(ws + WS_WFAST);
        float*  wT4    = ws + WS_WT4;
        int*    flagp  = (int*)(ws + WS_FLAG);
        if (idx < 64 * IN_F) {
            int o = idx & 63, i = idx >> 6;
            float s  = scale[o * IN_F + i];
            float tr = trans[o * IN_F + i];
            if (s != 1.0f || tr != 0.0f) atomicOr(flagp, 1);
            float a  = 1.0f / s;
            float b  = -tr * a;
            float wq = 0.8673250705840776f * ww[o * IN_F + i];   // 2/(sqrt(3)*pi^0.25)
            float bb = bw[o * IN_F + i];
            wpack[i * 64 + o] = make_float4(a, b, wq, bb);
            wfast2[(i >> 1) * 128 + o * 2 + (i & 1)] = make_float2(wq, bb);
        }
        int idx2 = idx - 64 * IN_F;
        if (idx2 >= 0 && idx2 < 24576) {
            int e = idx2 & 3; int rest = idx2 >> 2;
            int g = rest % 384; int k4 = rest / 384;
            int k = k4 * 4 + e; int dir = g / 192; int gg = g - dir * 192;
            const float* src = dir ? wihb : wihf;
            wT4[idx2] = src[gg * 64 + k];
        }
    }
    __threadfence();
    grid.sync();
    __threadfence();

    // ---------------- P1: WavKAN + BN + LN for this block's 32 rows ----------
    {
        int row0 = bid * 32;
        int o = t & 63, grp = t >> 6;              // 8 grps x 2 rows per subtile
        int fast = (*(const int*)(ws + WS_FLAG)) == 0;
        float bscale = bn_g[o] * fast_rsq(bn_v[o] + 1e-5f);
        float bshift = fmaf(-bn_m[o], bscale, bn_b[o]);
        float lg = ln_g[o], lb = ln_b[o];

        for (int st = 0; st < 2; ++st) {
            if (st) __syncthreads();               // subtile-0 reads complete
            float acc0 = 0.f, acc1 = 0.f;
            if (fast) {
                for (int idx = t; idx < 16 * IN_F; idx += 512) {
                    int r = idx / IN_F, i = idx - r * IN_F;
                    float x = x_seq[(row0 + st * 16 + r) * IN_F + i];
                    float u = x * x;
                    float phi = (u - 1.0f) * exp2f(u * NEG_HALF_L2E);
                    float sl  = x * fast_rcp(1.0f + exp2f(-LOG2E * x));
                    sm.s12.xs[idx] = make_float2(phi, sl);
                }
                __syncthreads();
                const float4* wf4 = (const float4*)(ws + WS_WFAST);
                const float4* xs4 = (const float4*)sm.s12.xs;
                const float4* xr0 = xs4 + (grp * 2 + 0) * 180;
                const float4* xr1 = xs4 + (grp * 2 + 1) * 180;
                #pragma unroll 2
                for (int i2 = 0; i2 < 180; ++i2) {
                    float4 wp = wf4[i2 * 64 + o];
                    float4 a = xr0[i2];
                    acc0 = fmaf(a.x, wp.x, acc0); acc0 = fmaf(a.y, wp.y, acc0);
                    acc0 = fmaf(a.z, wp.z, acc0); acc0 = fmaf(a.w, wp.w, acc0);
                    float4 b = xr1[i2];
                    acc1 = fmaf(b.x, wp.x, acc1); acc1 = fmaf(b.y, wp.y, acc1);
                    acc1 = fmaf(b.z, wp.z, acc1); acc1 = fmaf(b.w, wp.w, acc1);
                }
            } else {
                for (int idx = t; idx < 16 * IN_F; idx += 512) {
                    int r = idx / IN_F, i = idx - r * IN_F;
                    float x = x_seq[(row0 + st * 16 + r) * IN_F + i];
                    float sl = x * fast_rcp(1.0f + exp2f(-LOG2E * x));
                    sm.s12.xs[idx] = make_float2(x, sl);
                }
                __syncthreads();
                const float4* wpack = (const float4*)(ws + WS_WPACK);
                const float2* xr0 = sm.s12.xs + (grp * 2 + 0) * IN_F;
                const float2* xr1 = sm.s12.xs + (grp * 2 + 1) * IN_F;
                for (int i = 0; i < IN_F; ++i) {
                    float4 wp = wpack[i * 64 + o];
                    {
                        float2 xsv = xr0[i];
                        float xsc = fmaf(xsv.x, wp.x, wp.y); float u = xsc * xsc;
                        float e = exp2f(u * NEG_HALF_L2E);
                        acc0 = fmaf((u - 1.0f) * e, wp.z, acc0);
                        acc0 = fmaf(xsv.y, wp.w, acc0);
                    }
                    {
                        float2 xsv = xr1[i];
                        float xsc = fmaf(xsv.x, wp.x, wp.y); float u = xsc * xsc;
                        float e = exp2f(u * NEG_HALF_L2E);
                        acc1 = fmaf((u - 1.0f) * e, wp.z, acc1);
                        acc1 = fmaf(xsv.y, wp.w, acc1);
                    }
                }
            }
            float vals[2] = {acc0, acc1};
            #pragma unroll
            for (int rr = 0; rr < 2; ++rr) {
                float y = fmaf(vals[rr], bscale, bshift);
                float s = y;
                #pragma unroll
                for (int m = 1; m < 64; m <<= 1) s += __shfl_xor(s, m, 64);
                float mu = s * (1.0f / 64.0f);
                float d = y - mu;
                float s2 = d * d;
                #pragma unroll
                for (int m = 1; m < 64; m <<= 1) s2 += __shfl_xor(s2, m, 64);
                float rstd = fast_rsq(s2 * (1.0f / 64.0f) + 1e-5f);
                sm.s12.xs2[(st * 16 + grp * 2 + rr) * 64 + o] = fmaf(d * rstd, lg, lb);
            }
        }
        __syncthreads();                           // xs2 complete

        // ------------ P2: gi for these 32 rows, k4-outer / acc[32] ----------
        if (t < 384) {
            const float4* wT4 = (const float4*)(ws + WS_WT4);
            int dir = t / 192, gg = t - dir * 192;
            float bih = dir ? bihb[gg] : bihf[gg];
            float acc[32];
            #pragma unroll
            for (int j = 0; j < 32; ++j) acc[j] = bih;
            const float4* x4 = (const float4*)sm.s12.xs2;
            for (int k4 = 0; k4 < 16; ++k4) {
                float4 wv = wT4[k4 * 384 + t];
                #pragma unroll
                for (int j = 0; j < 32; ++j) {
                    float4 xv = x4[j * 16 + k4];
                    acc[j] = fmaf(xv.x, wv.x, acc[j]);
                    acc[j] = fmaf(xv.y, wv.y, acc[j]);
                    acc[j] = fmaf(xv.z, wv.z, acc[j]);
                    acc[j] = fmaf(xv.w, wv.w, acc[j]);
                }
            }
            #pragma unroll
            for (int j = 0; j < 32; ++j) gi[(size_t)(row0 + j) * 384 + t] = acc[j];
        }
    }
    __threadfence();
    grid.sync();
    __threadfence();

    // ---------------- P3: GRU recurrence (blocks 0..127; R4 body) -----------
    if (bid < 128) {
        int lane = t & 63, g = t >> 6;
        bool act = t < 192;
        int b = bid & 63, dirg = bid >> 6;
        const float* whh = dirg ? whhb : whhf;
        const float* bhh = dirg ? bhhb : bhhf;
        float w[64];
        float bias = 0.f, h = 0.f;
        const float* gsrc = gi + (size_t)(b * SEQ) * 384 + dirg * 192 + t;
#define GOFF(s) ((dirg ? (SEQ - 1 - (s)) : (s)) * 384)
        if (act) {
            const float4* wrow = (const float4*)(whh + t * 64);
            #pragma unroll
            for (int q = 0; q < 16; ++q) {
                float4 a = wrow[q];
                w[4*q] = a.x; w[4*q+1] = a.y; w[4*q+2] = a.z; w[4*q+3] = a.w;
            }
            bias = bhh[t];
            #pragma unroll 8
            for (int q = 0; q < 64; ++q) sm.s3.gi_l[q * 192 + t] = gsrc[GOFF(q)];
        }
        __syncthreads();

        for (int ss = 0; ss < SEQ; ++ss) {
            if (ss == 64) {
                __syncthreads();                   // phase-1 slot reads done
                if (act) {
                    #pragma unroll 8
                    for (int q = 0; q < 64; ++q)
                        sm.s3.gi_l[q * 192 + t] = gsrc[GOFF(64 + q)];
                }
                __syncthreads();                   // refill visible
            }
            int ssl = ss & 63, p = ss & 1;
            float inv = 0.f;
            if (act) {
                float giv = sm.s3.gi_l[ssl * 192 + t];
                inv       = sm.s3.gi_l[ssl * 192 + 128 + lane];
                float acc0 = bias, acc1 = 0.f;
                #pragma unroll
                for (int c = 0; c < 4; ++c) {
                    float sh[16];
                    #pragma unroll
                    for (int j = 0; j < 16; ++j) sh[j] = readlane_f(h, c * 16 + j);
                    #pragma unroll
                    for (int j = 0; j < 16; j += 2) {
                        acc0 = fmaf(w[c * 16 + j],     sh[j],     acc0);
                        acc1 = fmaf(w[c * 16 + j + 1], sh[j + 1], acc1);
                    }
                }
                float a = acc0 + acc1;
                float v = (g == 2) ? a : sigmoid_(giv + a);
                sm.s3.ex[p][t] = v;
            }
            __syncthreads();
            if (act) {
                float r  = sm.s3.ex[p][lane];
                float z  = sm.s3.ex[p][64 + lane];
                float an = sm.s3.ex[p][128 + lane];
                float n = tanh_(fmaf(r, an, inv));
                h = fmaf(z, h - n, n);             // (1-z)*n + z*h
            }
        }
#undef GOFF
        if (act && g == 0) hc[b * 128 + dirg * 64 + lane] = h;
    }
    __threadfence();
    grid.sync();
    __threadfence();

    // ---------------- P4: classifier head (blocks 0..63) --------------------
    if (bid < 64) {
        if (t < 64) {
            sm.s4.hr[t]      = hc[bid * 128 + t];
            sm.s4.hr[64 + t] = hc[bid * 128 + 64 + t];
        }
        __syncthreads();
        if (t < 64) {
            float acc = fc1b[t];
            const float4* w4 = (const float4*)(fc1w + t * 128);
            const float4* h4 = (const float4*)sm.s4.hr;
            #pragma unroll 8
            for (int k4 = 0; k4 < 32; ++k4) {
                float4 wv = w4[k4]; float4 hv = h4[k4];
                acc = fmaf(hv.x, wv.x, acc); acc = fmaf(hv.y, wv.y, acc);
                acc = fmaf(hv.z, wv.z, acc); acc = fmaf(hv.w, wv.w, acc);
            }
            sm.s4.h1[t] = fmaxf(acc, 0.0f);
        }
        __syncthreads();
        if (t < NCLS) {
            float acc2 = fc2b[t];
            const float* wr = fc2w + t * 64;
            #pragma unroll 8
            for (int k = 0; k < 64; ++k) acc2 = fmaf(sm.s4.h1[k], wr[k], acc2);
            out[bid * NCLS + t] = acc2;
        }
    }
}

extern "C" void kernel_launch(void* const* d_in, const int* in_sizes, int n_in,
                              void* d_out, int out_size, void* d_ws, size_t ws_size,
                              hipStream_t stream) {
    const float* x_seq = (const float*)d_in[0];
    const float* wscal = (const float*)d_in[1];
    const float* wtran = (const float*)d_in[2];
    const float* wwght = (const float*)d_in[3];
    const float* bwght = (const float*)d_in[4];
    const float* bn_g  = (const float*)d_in[5];
    const float* bn_b  = (const float*)d_in[6];
    const float* bn_m  = (const float*)d_in[7];
    const float* bn_v  = (const float*)d_in[8];
    const float* ln_g  = (const float*)d_in[9];
    const float* ln_b  = (const float*)d_in[10];
    const float* wihf  = (const float*)d_in[11];
    const float* whhf  = (const float*)d_in[12];
    const float* bihf  = (const float*)d_in[13];
    const float* bhhf  = (const float*)d_in[14];
    const float* wihb  = (const float*)d_in[15];
    const float* whhb  = (const float*)d_in[16];
    const float* bihb  = (const float*)d_in[17];
    const float* bhhb  = (const float*)d_in[18];
    const float* fc1w  = (const float*)d_in[19];
    const float* fc1b  = (const float*)d_in[20];
    const float* fc2w  = (const float*)d_in[21];
    const float* fc2b  = (const float*)d_in[22];
    float* ws  = (float*)d_ws;
    float* out = (float*)d_out;

    hipMemsetAsync(ws + WS_FLAG, 0, sizeof(int), stream);
    void* args[] = {
        (void*)&x_seq, (void*)&wscal, (void*)&wtran, (void*)&wwght, (void*)&bwght,
        (void*)&bn_g, (void*)&bn_b, (void*)&bn_m, (void*)&bn_v,
        (void*)&ln_g, (void*)&ln_b,
        (void*)&wihf, (void*)&wihb, (void*)&bihf, (void*)&bihb,
        (void*)&whhf, (void*)&bhhf, (void*)&whhb, (void*)&bhhb,
        (void*)&fc1w, (void*)&fc1b, (void*)&fc2w, (void*)&fc2b,
        (void*)&ws, (void*)&out
    };
    hipLaunchCooperativeKernel((const void*)mega_kernel, dim3(256), dim3(512),
                               args, 0, stream);
}